// Round 2
// baseline (111.076 us; speedup 1.0000x reference)
//
#include <hip/hip_runtime.h>

// GraphAttentionNet: x[8192,128] -> Q,K,V = relu(x W^T + b) [8192,64]
// out = softmax(Q K^T / 8) V + Q   (fp32 out)
//
// Plan: bf16 MFMA everywhere (threshold is ~2% of absmax; bf16 ~0.4%).
// k1: QKV projection (MFMA 16x16x32), stores Qb (bf16, pre-scaled by
//     0.125*log2e so softmax is base-2), Kb (bf16), Vt = V^T (bf16), Qf (f32).
// k2: flash attention with kv-split; swapped QK^T (mfma(K,Q^T)) so each lane
//     owns one q-row -> cheap softmax; P redistributed to PV B-frag via shfl.
// k3: merge split partials + residual.

typedef __attribute__((ext_vector_type(8))) __bf16 bf16x8;
typedef __attribute__((ext_vector_type(4))) float f32x4;

constexpr int N_ROWS = 8192;
constexpr int CDIM   = 128;
constexpr int DKV    = 64;   // DK == DV == 64
constexpr float SCALE_Q = 0.125f * 1.4426950408889634f; // 1/sqrt(64) * log2(e)

__device__ __forceinline__ float fast_exp2(float x) {
    return __builtin_amdgcn_exp2f(x);   // v_exp_f32 (base-2)
}

__device__ __forceinline__ unsigned short f2bf(float x) {
    union { float f; unsigned u; } v; v.f = x;
    unsigned r = v.u + 0x7fffu + ((v.u >> 16) & 1u);   // RNE
    return (unsigned short)(r >> 16);
}

union Frag {
    unsigned u32[4];
    unsigned short u16[8];
    bf16x8 b;
    f32x4 f;
};

// ---------------------------------------------------------------- QKV ------
__global__ __launch_bounds__(128) void qkv_kernel(
    const float* __restrict__ x,
    const float* __restrict__ Wq, const float* __restrict__ bq,
    const float* __restrict__ Wk, const float* __restrict__ bk,
    const float* __restrict__ Wv, const float* __restrict__ bv,
    unsigned short* __restrict__ Qb, unsigned short* __restrict__ Kb,
    unsigned short* __restrict__ Vt, float* __restrict__ Qf)
{
    const int tid = threadIdx.x;
    const int w  = tid >> 6;       // wave 0..1
    const int l  = tid & 63;
    const int g  = l >> 4;         // lane quarter
    const int lm = l & 15;
    const int n_base = blockIdx.x * 32 + w * 16;

    // A-fragments of x rows n_base..n_base+15 (fp32 -> bf16)
    bf16x8 af[4];
    {
        const float* xrow = x + (size_t)(n_base + lm) * CDIM;
        #pragma unroll
        for (int s = 0; s < 4; ++s) {
            f32x4 lo = *(const f32x4*)(xrow + s * 32 + g * 8);
            f32x4 hi = *(const f32x4*)(xrow + s * 32 + g * 8 + 4);
            Frag fr;
            #pragma unroll
            for (int j = 0; j < 4; ++j) { fr.u16[j] = f2bf(lo[j]); fr.u16[4 + j] = f2bf(hi[j]); }
            af[s] = fr.b;
        }
    }

    const float* Ws[3] = {Wq, Wk, Wv};
    const float* Bs[3] = {bq, bk, bv};
    #pragma unroll
    for (int mat = 0; mat < 3; ++mat) {
        #pragma unroll
        for (int ct = 0; ct < 4; ++ct) {
            const int f = ct * 16 + lm;                 // output feature (B col)
            const float* wrow = Ws[mat] + (size_t)f * CDIM;
            f32x4 acc = {0.f, 0.f, 0.f, 0.f};
            #pragma unroll
            for (int s = 0; s < 4; ++s) {
                f32x4 lo = *(const f32x4*)(wrow + s * 32 + g * 8);
                f32x4 hi = *(const f32x4*)(wrow + s * 32 + g * 8 + 4);
                Frag fr;
                #pragma unroll
                for (int j = 0; j < 4; ++j) { fr.u16[j] = f2bf(lo[j]); fr.u16[4 + j] = f2bf(hi[j]); }
                acc = __builtin_amdgcn_mfma_f32_16x16x32_bf16(af[s], fr.b, acc, 0, 0, 0);
            }
            const float bias = Bs[mat][f];
            #pragma unroll
            for (int j = 0; j < 4; ++j) {
                const int n = n_base + g * 4 + j;       // D row = A row
                const float v = fmaxf(acc[j] + bias, 0.f);
                if (mat == 0) {
                    Qf[(size_t)n * DKV + f] = v;
                    Qb[(size_t)n * DKV + f] = f2bf(v * SCALE_Q);
                } else if (mat == 1) {
                    Kb[(size_t)n * DKV + f] = f2bf(v);
                } else {
                    Vt[(size_t)f * N_ROWS + n] = f2bf(v); // store V transposed
                }
            }
        }
    }
}

// ---------------------------------------------------------- attention ------
__global__ __launch_bounds__(256) void attn_kernel(
    const unsigned short* __restrict__ Qb, const unsigned short* __restrict__ Kb,
    const unsigned short* __restrict__ Vt,
    float* __restrict__ PartO, float* __restrict__ PartML,
    int kv_per_split)
{
    __shared__ __align__(16) unsigned short K_lds[64 * 64]; // [kv][dk], XOR-swizzled
    __shared__ __align__(16) unsigned short V_lds[64 * 64]; // [dv][kv], XOR-swizzled

    const int tid = threadIdx.x;
    const int w  = tid >> 6;       // wave 0..3 -> q sub-tile
    const int l  = tid & 63;
    const int g  = l >> 4;
    const int lm = l & 15;
    const int qb = blockIdx.x;
    const int sp = blockIdx.y;
    const int q0 = qb * 64 + w * 16;
    const int kv0 = sp * kv_per_split;

    // Hoisted Q B-fragments: B[k][col] -> Qb[q0+lm][32s + 8g + j] (row-major 16B)
    bf16x8 qf[2];
    #pragma unroll
    for (int s = 0; s < 2; ++s)
        qf[s] = *(const bf16x8*)(Qb + (size_t)(q0 + lm) * DKV + s * 32 + g * 8);

    const f32x4 vzero = {0.f, 0.f, 0.f, 0.f};
    f32x4 o[4];
    #pragma unroll
    for (int d = 0; d < 4; ++d) o[d] = vzero;
    float m = -3.0e38f;
    float lsum = 0.f;

    const int ntiles = kv_per_split >> 6;
    for (int t = 0; t < ntiles; ++t) {
        const int kvt = kv0 + (t << 6);
        __syncthreads(); // protect LDS from previous iteration's readers
        // Stage K tile [64 kv][64 dk] and V^T tile [64 dv][64 kv], swizzled:
        // lds[row*128 + (xb ^ ((row&7)<<4))] = global[row][xb]
        #pragma unroll
        for (int c = 0; c < 2; ++c) {
            const int chunk = tid + c * 256;            // 0..511
            const int row = chunk >> 3;                 // 0..63
            const int xb  = (chunk & 7) << 4;           // 16B chunk in 128B row
            const int dst = row * 128 + (xb ^ ((row & 7) << 4));
            *(f32x4*)((char*)K_lds + dst) =
                *(const f32x4*)((const char*)Kb + (size_t)(kvt + row) * 128 + xb);
            *(f32x4*)((char*)V_lds + dst) =
                *(const f32x4*)((const char*)Vt + (size_t)row * (N_ROWS * 2) + (size_t)kvt * 2 + xb);
        }
        __syncthreads();

        // S^T = K * Q^T : D rows = kv, D cols = q (lane lm owns one q column)
        f32x4 st[4];
        #pragma unroll
        for (int kt = 0; kt < 4; ++kt) {
            st[kt] = vzero;
            #pragma unroll
            for (int s = 0; s < 2; ++s) {
                const int row = kt * 16 + lm;
                const int xb = (s * 64 + g * 16) ^ ((row & 7) << 4);
                bf16x8 a = *(const bf16x8*)((const char*)K_lds + row * 128 + xb);
                st[kt] = __builtin_amdgcn_mfma_f32_16x16x32_bf16(a, qf[s], st[kt], 0, 0, 0);
            }
        }

        // Online softmax, base-2 (scale folded into Qb). Lane holds kv = 16kt+4g+j
        // for q = lm; max/sum over kv needs only per-lane reduce + xor16/32.
        float tmax = -3.0e38f;
        #pragma unroll
        for (int kt = 0; kt < 4; ++kt)
            #pragma unroll
            for (int j = 0; j < 4; ++j)
                tmax = fmaxf(tmax, st[kt][j]);
        tmax = fmaxf(tmax, __shfl_xor(tmax, 16));
        tmax = fmaxf(tmax, __shfl_xor(tmax, 32));
        const float mnew = fmaxf(m, tmax);
        const float alpha = fast_exp2(m - mnew);
        m = mnew;
        lsum *= alpha;
        #pragma unroll
        for (int d = 0; d < 4; ++d)
            #pragma unroll
            for (int j = 0; j < 4; ++j)
                o[d][j] *= alpha;

        unsigned pk[4][2]; // bf16 pairs: pk[kt][h] = P[lm][16kt+4g+2h .. +1]
        #pragma unroll
        for (int kt = 0; kt < 4; ++kt) {
            float p0 = fast_exp2(st[kt][0] - mnew);
            float p1 = fast_exp2(st[kt][1] - mnew);
            float p2 = fast_exp2(st[kt][2] - mnew);
            float p3 = fast_exp2(st[kt][3] - mnew);
            lsum += (p0 + p1) + (p2 + p3);
            pk[kt][0] = (unsigned)f2bf(p0) | ((unsigned)f2bf(p1) << 16);
            pk[kt][1] = (unsigned)f2bf(p2) | ((unsigned)f2bf(p3) << 16);
        }

        // PV: O^T += V^T * P^T. B-frag elem j = P[lm][32*s2 + 8g + j]; gather
        // the pairs from sibling lane groups via shfl (src has same lm).
        const int src0 = (g & 1) * 32 + lm;
        const int src1 = src0 + 16;
        const bool hi_half = (g >= 2);
        #pragma unroll
        for (int s2 = 0; s2 < 2; ++s2) {
            Frag pf;
            #pragma unroll
            for (int u = 0; u < 4; ++u) {
                const int src = (u & 2) ? src1 : src0;
                const unsigned va = __shfl(pk[2 * s2][u & 1], src);
                const unsigned vb = __shfl(pk[2 * s2 + 1][u & 1], src);
                pf.u32[u] = hi_half ? vb : va;
            }
            #pragma unroll
            for (int d = 0; d < 4; ++d) {
                const int row = d * 16 + lm;
                const int xb = (s2 * 64 + g * 16) ^ ((row & 7) << 4);
                bf16x8 a = *(const bf16x8*)((const char*)V_lds + row * 128 + xb);
                o[d] = __builtin_amdgcn_mfma_f32_16x16x32_bf16(a, pf.b, o[d], 0, 0, 0);
            }
        }
    }

    // lsum covered only this lane group's kv subset; combine the 4 groups.
    lsum += __shfl_xor(lsum, 16);
    lsum += __shfl_xor(lsum, 32);

    const int qt = qb * 4 + w;
    float* po = PartO + (size_t)(sp * (N_ROWS / 16) + qt) * 16 * 64; // [q16][dv64]
    #pragma unroll
    for (int d = 0; d < 4; ++d)
        #pragma unroll
        for (int j = 0; j < 4; ++j)
            po[(size_t)lm * 64 + d * 16 + g * 4 + j] = o[d][j];
    if (g == 0) {
        float* pml = PartML + (size_t)(sp * (N_ROWS / 16) + qt) * 32;
        pml[lm] = m;
        pml[16 + lm] = lsum;
    }
}

// -------------------------------------------------------------- merge ------
__global__ __launch_bounds__(64) void merge_kernel(
    const float* __restrict__ PartO, const float* __restrict__ PartML,
    const float* __restrict__ Qf, float* __restrict__ out, int split)
{
    const int qt = blockIdx.x;   // 0..511
    const int t  = threadIdx.x;  // dv 0..63
    for (int qr = 0; qr < 16; ++qr) {
        const int q = qt * 16 + qr;
        float M = -3.0e38f;
        for (int s = 0; s < split; ++s)
            M = fmaxf(M, PartML[(size_t)(s * (N_ROWS / 16) + qt) * 32 + qr]);
        float L = 0.f;
        for (int s = 0; s < split; ++s) {
            const float* pml = PartML + (size_t)(s * (N_ROWS / 16) + qt) * 32;
            L += pml[16 + qr] * fast_exp2(pml[qr] - M);
        }
        const float invL = 1.f / L;
        float acc = 0.f;
        for (int s = 0; s < split; ++s) {
            const float ms = PartML[(size_t)(s * (N_ROWS / 16) + qt) * 32 + qr];
            acc += PartO[((size_t)(s * (N_ROWS / 16) + qt) * 16 + qr) * 64 + t] * fast_exp2(ms - M);
        }
        out[(size_t)q * 64 + t] = acc * invL + Qf[(size_t)q * 64 + t];
    }
}

// ------------------------------------------------------------- launch ------
extern "C" void kernel_launch(void* const* d_in, const int* in_sizes, int n_in,
                              void* d_out, int out_size, void* d_ws, size_t ws_size,
                              hipStream_t stream)
{
    const float* x  = (const float*)d_in[0];
    const float* Wq = (const float*)d_in[1];
    const float* bq = (const float*)d_in[2];
    const float* Wk = (const float*)d_in[3];
    const float* bk = (const float*)d_in[4];
    const float* Wv = (const float*)d_in[5];
    const float* bv = (const float*)d_in[6];
    float* out = (float*)d_out;

    char* ws = (char*)d_ws;
    size_t off = 0;
    auto take = [&](size_t bytes) {
        char* p = ws + off;
        off += (bytes + 255) & ~(size_t)255;
        return p;
    };
    unsigned short* Qb = (unsigned short*)take((size_t)N_ROWS * DKV * 2);
    unsigned short* Kb = (unsigned short*)take((size_t)N_ROWS * DKV * 2);
    unsigned short* Vt = (unsigned short*)take((size_t)DKV * N_ROWS * 2);
    float*          Qf = (float*)take((size_t)N_ROWS * DKV * 4);

    // kv-split for occupancy; shrink if workspace is small (deterministic in ws_size).
    int split = 8;
    const size_t per_split = (size_t)(N_ROWS / 16) * 16 * 64 * 4
                           + (size_t)(N_ROWS / 16) * 32 * 4 + 512;
    while (split > 1 && off + (size_t)split * per_split > ws_size) split >>= 1;

    float* PartO  = (float*)take((size_t)split * (N_ROWS / 16) * 16 * 64 * 4);
    float* PartML = (float*)take((size_t)split * (N_ROWS / 16) * 32 * 4);

    qkv_kernel<<<dim3(N_ROWS / 32), dim3(128), 0, stream>>>(
        x, Wq, bq, Wk, bk, Wv, bv, Qb, Kb, Vt, Qf);
    attn_kernel<<<dim3(N_ROWS / 64, split), dim3(256), 0, stream>>>(
        Qb, Kb, Vt, PartO, PartML, N_ROWS / split);
    merge_kernel<<<dim3(N_ROWS / 16), dim3(64), 0, stream>>>(
        PartO, PartML, Qf, out, split);
}